// Round 4
// baseline (5151.395 us; speedup 1.0000x reference)
//
#include <hip/hip_runtime.h>

// ---------- types ----------
typedef _Float16 h8 __attribute__((ext_vector_type(8)));
typedef _Float16 h4 __attribute__((ext_vector_type(4)));
typedef float    f4 __attribute__((ext_vector_type(4)));

#define NBLK 256   // persistent grid = 256 blocks = 1 per CU

__device__ __forceinline__ float sigm(float x) {
    return 1.0f / (1.0f + __expf(-x));
}
__device__ __forceinline__ float tanh_fast(float x) {
    return 1.0f - 2.0f / (__expf(2.0f * x) + 1.0f);   // saturates correctly at +/-inf
}

// Split grid barrier, PER-MG (the two 64-batch-row halves never exchange data,
// so each barrier spans only 128 blocks: 4 groups x 32 blocks).
// Fence hygiene identical to the verified baseline: exactly ONE release fence
// (wbl2) before arrival and ONE acquire fence (inv) after the spin, per block
// per step, tid 0 only. Arrival/spin use RELAXED agent atomics.
// FLAT wait: pollers read the 4 group counters directly (4 parallel LLC loads,
// 256 B apart) and compare the sum — no root counter, one LLC hop shorter.
// Monotonic counters + relaxed loads => polled sum is a lower bound on true
// arrivals => can never exit early, only late. Provably equivalent.
__device__ __forceinline__ void bar_arrive(unsigned* grp, int g) {
    __syncthreads();   // h stores acked to L2 (vmcnt(0) before s_barrier);
                       // out stores are DEFERRED past this point (see caller)
    if (threadIdx.x == 0) {
        __builtin_amdgcn_fence(__ATOMIC_RELEASE, "agent");   // flush dirty L2 lines once
        __hip_atomic_fetch_add(&grp[g * 64], 1u, __ATOMIC_RELAXED,
                               __HIP_MEMORY_SCOPE_AGENT);
    }
    // NO trailing sync: other waves fall through into h-independent work.
}
__device__ __forceinline__ void bar_wait(unsigned* grp, int mg, unsigned barno) {
    if (threadIdx.x == 0) {
        const unsigned tgt = (barno + 1u) * 128u;   // 4 groups x 32 blocks per round
        unsigned* base = &grp[mg * 4 * 64];
        unsigned spins = 0;
        for (;;) {
            unsigned s0 = __hip_atomic_load(&base[0],   __ATOMIC_RELAXED,
                                            __HIP_MEMORY_SCOPE_AGENT);
            unsigned s1 = __hip_atomic_load(&base[64],  __ATOMIC_RELAXED,
                                            __HIP_MEMORY_SCOPE_AGENT);
            unsigned s2 = __hip_atomic_load(&base[128], __ATOMIC_RELAXED,
                                            __HIP_MEMORY_SCOPE_AGENT);
            unsigned s3 = __hip_atomic_load(&base[192], __ATOMIC_RELAXED,
                                            __HIP_MEMORY_SCOPE_AGENT);
            if (s0 + s1 + s2 + s3 >= tgt) break;
            __builtin_amdgcn_s_sleep(2);
            if (++spins > (1u << 24)) break;   // safety valve: corrupt-but-return
        }
        __builtin_amdgcn_fence(__ATOMIC_ACQUIRE, "agent");   // drop stale L2 lines once
    }
    __syncthreads();   // also drains the overlapped nt out-stores + x loads
}

// ---------- prep: zero counters + hb0, fp32 x -> fp16 ----------
__global__ void prep_kernel(const float* __restrict__ x, _Float16* __restrict__ xbuf,
                            unsigned* __restrict__ ctr, unsigned* __restrict__ hb0u) {
    const int gtid = blockIdx.x * blockDim.x + threadIdx.x;
    if (gtid < 1024) ctr[gtid] = 0u;          // grp[8] (256-B stride)
    if (gtid < 65536) hb0u[gtid] = 0u;        // hb0: 128x1024 fp16 = 256 KB
    const f4* src = (const f4*)x;
    h4* dst = (h4*)xbuf;
    const int stride = gridDim.x * blockDim.x;    // 524288
    for (int i = gtid; i < 8388608; i += stride)  // T*B*D/4
        dst[i] = __builtin_convertvector(src[i], h4);
}

// ---------- persistent LSTM ----------
// 256 blocks x 256 threads. Block b: mg = b>>7 (rows mg*64..+63), ug = b&127,
// units u0 = ug*8 .. +7, all 4 gates -> 32 preact cols (2 MFMA n-tiles).
// ALL of W (K=2048) in LDS, conflict-free chunk layout (see staging below).
// Loop structure per step t:
//   [a-regs already hold the x-half partial sums for step t]
//   bar_wait(t-1)            <- h(t) now globally visible
//   h-half MFMAs (kc 32..63) <- the only h-dependent GEMM work
//   epilogue: activations, c/h update, store h(t+1) ONLY (small L2-acked drain)
//   bar_arrive(t)            <- release h(t+1)
//   nt out stores for step t <- fire-and-forget, drain overlapped w/ next spin
//   x-half MFMAs for t+1     <- executes INSIDE the barrier window
#define XHALF                                                                  \
    _Pragma("unroll")                                                          \
    for (int kc = 0; kc < 32; kc += 2) {                                       \
        h8 av0 = *(const h8*)(xA + kc * 32);                                   \
        h8 av1 = *(const h8*)(xA + kc * 32 + 32);                              \
        h8 b00 = *(const h8*)&wsm[kc * 1024 + boff];                           \
        h8 b10 = *(const h8*)&wsm[kc * 1024 + boff + 512];                     \
        h8 b01 = *(const h8*)&wsm[(kc + 1) * 1024 + boff];                     \
        h8 b11 = *(const h8*)&wsm[(kc + 1) * 1024 + boff + 512];               \
        a00 = __builtin_amdgcn_mfma_f32_16x16x32_f16(av0, b00, a00, 0, 0, 0);  \
        a10 = __builtin_amdgcn_mfma_f32_16x16x32_f16(av0, b10, a10, 0, 0, 0);  \
        a01 = __builtin_amdgcn_mfma_f32_16x16x32_f16(av1, b01, a01, 0, 0, 0);  \
        a11 = __builtin_amdgcn_mfma_f32_16x16x32_f16(av1, b11, a11, 0, 0, 0);  \
    }

__global__ __launch_bounds__(256, 1)
void lstm_kernel(const _Float16* __restrict__ xbuf,
                 _Float16* __restrict__ hb0, _Float16* __restrict__ hb1,
                 const float* __restrict__ Wf, const float* __restrict__ bfp,
                 const float* __restrict__ Wi, const float* __restrict__ bip,
                 const float* __restrict__ Wg, const float* __restrict__ bgp,
                 const float* __restrict__ Wo, const float* __restrict__ bop,
                 float* __restrict__ out,
                 unsigned* __restrict__ grp) {
    __shared__ _Float16 wsm[64 * 1024];   // 128 KB: full W slice, chunked

    const int tid = threadIdx.x;
    const int bid = blockIdx.x;
    const int mg = bid >> 7;
    const int ug = bid & 127;
    const int u0 = ug << 3;
    const int g  = mg * 4 + (bid & 3);    // barrier group: 32 blocks each

    const float* WSEL[4] = {Wf, Wi, Wg, Wo};

    // ---- stage W slice (32 cols x 2048 k) fp32 -> fp16 LDS, chunked ----
    // f16 idx = kc*1024 + tile*512 + quad*128 + row16*8 + j
    // (kc = k>>5, quad = (k>>3)&3, j = k&7, col = tile*16 + row16)
    // Read addr for lane L (= quad*16+row16): byte = kc*2048 + tile*1024 + L*16
    //   -> perfectly contiguous 16 B/lane -> zero bank conflicts.
    {
        const int col = tid & 31;                  // preact col
        const int kseg = tid >> 5;                 // 0..7, 256 k each
        const float* srcp = WSEL[col >> 3] + (size_t)(u0 + (col & 7)) * 2048
                          + kseg * 256;
        const int cbase = (col >> 4) * 512 + (col & 15) * 8;
#pragma unroll 8
        for (int k4 = 0; k4 < 256; k4 += 4) {
            const int k = kseg * 256 + k4;
            f4 v = *(const f4*)(srcp + k4);
            h4 hv = __builtin_convertvector(v, h4);
            *(h4*)&wsm[(k >> 5) * 1024 + cbase + ((k >> 3) & 3) * 128 + (k & 7)] = hv;
        }
    }

    // ---- per-lane constants ----
    const int lane  = tid & 63;
    const int wv    = tid >> 6;        // wave -> m-strip
    const int row16 = lane & 15;
    const int quad  = lane >> 4;
    const int uu    = lane & 7;

    __syncthreads();   // W staged (block-local)

    const float bias_f = bfp[u0 + uu];
    const float bias_i = bip[u0 + uu];
    const float bias_g = bgp[u0 + uu];
    const float bias_o = bop[u0 + uu];

    const int zrow = mg * 64 + wv * 16 + row16;
    const int boff = quad * 128 + row16 * 8;      // lane*8 f16 = lane*16 B
    const int drow = mg * 64 + wv * 16 + quad * 4;
    const bool writer = (lane & 8) == 0;
    const bool himask = (lane & 8) != 0;

    const _Float16* hbv[2] = {hb0, hb1};
    const size_t aoff = (size_t)zrow * 1024 + quad * 8;
    const _Float16* xbase = xbuf + aoff;
    const size_t obase = (size_t)drow * 1024 + u0 + uu;   // row j adds j*1024

    float cc[4] = {0.f, 0.f, 0.f, 0.f};
    float hnv[4];                                  // step-t h values, stored late

    // ---- prologue: x-half for t = 0 (h(0)=0 already staged by prep) ----
    f4 a00 = {0.f,0.f,0.f,0.f}, a01 = {0.f,0.f,0.f,0.f};
    f4 a10 = {0.f,0.f,0.f,0.f}, a11 = {0.f,0.f,0.f,0.f};
    {
        const _Float16* xA = xbase;
        XHALF
    }

    for (int t = 0; t < 256; ++t) {
        if (t) bar_wait(grp, mg, (unsigned)(t - 1));   // h(t) visible

        const _Float16* hA = hbv[t & 1] + aoff;
        _Float16* hw = (_Float16*)hbv[(t + 1) & 1];

        // h half: k chunks 32..63 (the only h-dependent work)
#pragma unroll
        for (int kc = 32; kc < 64; kc += 2) {
            h8 av0 = *(const h8*)(hA + (kc - 32) * 32);
            h8 av1 = *(const h8*)(hA + (kc - 32) * 32 + 32);
            h8 b00 = *(const h8*)&wsm[kc * 1024 + boff];
            h8 b10 = *(const h8*)&wsm[kc * 1024 + boff + 512];
            h8 b01 = *(const h8*)&wsm[(kc + 1) * 1024 + boff];
            h8 b11 = *(const h8*)&wsm[(kc + 1) * 1024 + boff + 512];
            a00 = __builtin_amdgcn_mfma_f32_16x16x32_f16(av0, b00, a00, 0, 0, 0);
            a10 = __builtin_amdgcn_mfma_f32_16x16x32_f16(av0, b10, a10, 0, 0, 0);
            a01 = __builtin_amdgcn_mfma_f32_16x16x32_f16(av1, b01, a01, 0, 0, 0);
            a11 = __builtin_amdgcn_mfma_f32_16x16x32_f16(av1, b11, a11, 0, 0, 0);
        }

        // ---- epilogue: gather gate pairs, activations, state update ----
        f4 s0 = a00 + a01;   // tile0: f|i preacts, col = lane&15
        f4 s1 = a10 + a11;   // tile1: g|o preacts
        float q0[4], q1[4];
#pragma unroll
        for (int j = 0; j < 4; ++j) {
            q0[j] = __shfl_xor(s0[j], 8, 64);
            q1[j] = __shfl_xor(s1[j], 8, 64);
        }
#pragma unroll
        for (int j = 0; j < 4; ++j) {
            float pf = himask ? q0[j] : s0[j];
            float pi = himask ? s0[j] : q0[j];
            float pg = himask ? q1[j] : s1[j];
            float po = himask ? s1[j] : q1[j];
            float fg = sigm(pf + bias_f);
            float ig = sigm(pi + bias_i);
            float gg = tanh_fast(pg + bias_g);
            float og = sigm(po + bias_o);
            float cn = fg * cc[j] + ig * gg;
            cc[j] = cn;
            float hn = og * tanh_fast(cn);
            hnv[j] = hn;
            if (writer)
                hw[obase + (size_t)j * 1024] = (_Float16)hn;   // feedback only:
                // the ONLY store that must drain before the release fence
        }

        if (t < 255) {
            bar_arrive(grp, g);                  // release h(t+1), arrive
            // deferred nt out stores for step t: fire-and-forget, acks drain
            // at the NEXT bar_wait's trailing __syncthreads, overlapped with
            // the spin + x-half GEMM (off the critical path)
            if (writer) {
                float* outb = out + (size_t)t * 131072;
#pragma unroll
                for (int j = 0; j < 4; ++j)
                    __builtin_nontemporal_store(hnv[j], &outb[obase + (size_t)j * 1024]);
            }
            // x-half for t+1: h-independent, runs inside the barrier window
            a00 = (f4){0.f,0.f,0.f,0.f}; a01 = (f4){0.f,0.f,0.f,0.f};
            a10 = (f4){0.f,0.f,0.f,0.f}; a11 = (f4){0.f,0.f,0.f,0.f};
            const _Float16* xA = xbase + (size_t)(t + 1) * 131072;
            XHALF
        } else if (writer) {
            // t = 255: no barrier follows; store outputs[255] + hx directly
            float* outb = out + (size_t)255 * 131072;
#pragma unroll
            for (int j = 0; j < 4; ++j) {
                __builtin_nontemporal_store(hnv[j], &outb[obase + (size_t)j * 1024]);
                __builtin_nontemporal_store(hnv[j], &out[33554432 + obase + (size_t)j * 1024]);
            }
        }
    }
    // cx
    if (writer) {
#pragma unroll
        for (int j = 0; j < 4; ++j)
            __builtin_nontemporal_store(
                cc[j], &out[33554432 + 131072 + obase + (size_t)j * 1024]);
    }
}

extern "C" void kernel_launch(void* const* d_in, const int* in_sizes, int n_in,
                              void* d_out, int out_size, void* d_ws, size_t ws_size,
                              hipStream_t stream) {
    const float* x  = (const float*)d_in[0];
    const float* Wf = (const float*)d_in[1];
    const float* bf = (const float*)d_in[2];
    const float* Wi = (const float*)d_in[3];
    const float* bi = (const float*)d_in[4];
    const float* Wg = (const float*)d_in[5];
    const float* bg = (const float*)d_in[6];
    const float* Wo = (const float*)d_in[7];
    const float* bo = (const float*)d_in[8];
    float* out = (float*)d_out;

    unsigned char* ws = (unsigned char*)d_ws;
    unsigned* grp  = (unsigned*)ws;                       // 8 counters, 256-B stride
    _Float16* hb0  = (_Float16*)(ws + 4096);              // 128x1024 fp16 (256 KB)
    _Float16* hb1  = (_Float16*)(ws + 4096 + 262144);
    _Float16* xbuf = (_Float16*)(ws + 4096 + 524288);     // 256x128x1024 fp16 (64 MB)

    prep_kernel<<<2048, 256, 0, stream>>>(x, xbuf, grp, (unsigned*)hb0);
    lstm_kernel<<<NBLK, 256, 0, stream>>>(xbuf, hb0, hb1,
                                          Wf, bf, Wi, bi, Wg, bg, Wo, bo,
                                          out, grp);
}

// Round 7
// 3798.912 us; speedup vs baseline: 1.3560x; 1.3560x over previous
//
#include <hip/hip_runtime.h>

// ---------- types ----------
typedef _Float16 h8 __attribute__((ext_vector_type(8)));
typedef _Float16 h4 __attribute__((ext_vector_type(4)));
typedef float    f4 __attribute__((ext_vector_type(4)));
typedef unsigned long long u64;

#define NBLK 256   // persistent grid = 256 blocks = 1 per CU

__device__ __forceinline__ float sigm(float x) {
    return 1.0f / (1.0f + __expf(-x));
}
__device__ __forceinline__ float tanh_fast(float x) {
    return 1.0f - 2.0f / (__expf(2.0f * x) + 1.0f);   // saturates correctly at +/-inf
}

// FENCE-FREE grid barrier (per-mg, 4 groups x 32 blocks).
// Rationale (R4 counters): MfmaUtil 4.4% / VALUBusy 4.8% -> ~17.5us/step idle.
// Work-hiding changes were neutral => the cost is INSIDE the barrier: 32
// blocks/XCD each issuing buffer_wbl2 + buffer_inv per step, serialized at the
// shared per-XCD L2. Fix: all cross-block data (the h ping-pong) moves to
// agent-scope ATOMIC loads/stores (sc1: bypass L1/L2, coherent at LLC), so no
// cache maintenance is needed at all.
// Release ordering: bar_arrive's __syncthreads emits s_waitcnt vmcnt(0) before
// s_barrier -> all waves' sc1 h-stores are LLC-visible before tid0's arrival
// RMW issues (vmcnt completion of an sc1 store = agent-visible, AMDGPUUsage).
// Acquire ordering: h loads are sc1 (always read LLC); they sit after the
// spin's control dependency + __syncthreads, so they observe LLC state no
// older than the counter value. No stale caches exist to invalidate.
__device__ __forceinline__ void bar_arrive(unsigned* grp, int g) {
    __syncthreads();   // s_waitcnt vmcnt(0): all sc1 h-stores acked at LLC
    if (threadIdx.x == 0) {
        __hip_atomic_fetch_add(&grp[g * 64], 1u, __ATOMIC_RELAXED,
                               __HIP_MEMORY_SCOPE_AGENT);
    }
    // NO trailing sync: other waves fall through into h-independent work.
}
__device__ __forceinline__ void bar_wait(unsigned* grp, int mg, unsigned barno) {
    if (threadIdx.x == 0) {
        const unsigned tgt = (barno + 1u) * 128u;   // 4 groups x 32 blocks per round
        unsigned* base = &grp[mg * 4 * 64];
        unsigned spins = 0;
        for (;;) {
            unsigned s0 = __hip_atomic_load(&base[0],   __ATOMIC_RELAXED,
                                            __HIP_MEMORY_SCOPE_AGENT);
            unsigned s1 = __hip_atomic_load(&base[64],  __ATOMIC_RELAXED,
                                            __HIP_MEMORY_SCOPE_AGENT);
            unsigned s2 = __hip_atomic_load(&base[128], __ATOMIC_RELAXED,
                                            __HIP_MEMORY_SCOPE_AGENT);
            unsigned s3 = __hip_atomic_load(&base[192], __ATOMIC_RELAXED,
                                            __HIP_MEMORY_SCOPE_AGENT);
            if (s0 + s1 + s2 + s3 >= tgt) break;
            __builtin_amdgcn_s_sleep(2);
            if (++spins > (1u << 24)) break;   // safety valve: corrupt-but-return
        }
    }
    __syncthreads();   // also drains the overlapped nt out-stores + x loads
}

// ---------- prep: zero counters + hb0, fp32 x -> fp16 ----------
__global__ void prep_kernel(const float* __restrict__ x, _Float16* __restrict__ xbuf,
                            unsigned* __restrict__ ctr, unsigned* __restrict__ hb0u) {
    const int gtid = blockIdx.x * blockDim.x + threadIdx.x;
    if (gtid < 1024) ctr[gtid] = 0u;          // grp[8] (256-B stride)
    if (gtid < 65536) hb0u[gtid] = 0u;        // hb0: 128x1024 fp16 = 256 KB
    const f4* src = (const f4*)x;
    h4* dst = (h4*)xbuf;
    const int stride = gridDim.x * blockDim.x;    // 524288
    for (int i = gtid; i < 8388608; i += stride)  // T*B*D/4
        dst[i] = __builtin_convertvector(src[i], h4);
}

// ---------- persistent LSTM ----------
// 256 blocks x 256 threads. Block b: mg = b>>7 (rows mg*64..+63), ug = b&127,
// units u0 = ug*8 .. +7, all 4 gates -> 32 preact cols (2 MFMA n-tiles).
// ALL of W (K=2048) in LDS, conflict-free chunk layout (see staging below).
// Loop structure per step t:
//   [a-regs already hold the x-half partial sums for step t]
//   bar_wait(t-1)            <- h(t) arrival count reached
//   h-half MFMAs (kc 32..63) <- A-fragments via sc1 atomic loads (LLC-fresh)
//   epilogue: activations, c/h update, h(t+1) via packed sc1 atomic stores
//   bar_arrive(t)            <- vmcnt(0)-drained stores, then counter RMW
//   nt out stores for step t <- fire-and-forget, drain overlapped w/ next spin
//   x-half MFMAs for t+1     <- executes INSIDE the barrier window
#define XHALF                                                                  \
    _Pragma("unroll")                                                          \
    for (int kc = 0; kc < 32; kc += 2) {                                       \
        h8 av0 = *(const h8*)(xA + kc * 32);                                   \
        h8 av1 = *(const h8*)(xA + kc * 32 + 32);                              \
        h8 b00 = *(const h8*)&wsm[kc * 1024 + boff];                           \
        h8 b10 = *(const h8*)&wsm[kc * 1024 + boff + 512];                     \
        h8 b01 = *(const h8*)&wsm[(kc + 1) * 1024 + boff];                     \
        h8 b11 = *(const h8*)&wsm[(kc + 1) * 1024 + boff + 512];               \
        a00 = __builtin_amdgcn_mfma_f32_16x16x32_f16(av0, b00, a00, 0, 0, 0);  \
        a10 = __builtin_amdgcn_mfma_f32_16x16x32_f16(av0, b10, a10, 0, 0, 0);  \
        a01 = __builtin_amdgcn_mfma_f32_16x16x32_f16(av1, b01, a01, 0, 0, 0);  \
        a11 = __builtin_amdgcn_mfma_f32_16x16x32_f16(av1, b11, a11, 0, 0, 0);  \
    }

// sc1 (LLC-coherent) h8 load: two agent-relaxed u64 atomic loads.
#define LDH8(dst, elemoff)                                                     \
    do {                                                                       \
        union { u64 q[2]; h8 v; } u_;                                          \
        u64* p_ = (u64*)(hA + (elemoff));                                      \
        u_.q[0] = __hip_atomic_load(p_,     __ATOMIC_RELAXED,                  \
                                    __HIP_MEMORY_SCOPE_AGENT);                 \
        u_.q[1] = __hip_atomic_load(p_ + 1, __ATOMIC_RELAXED,                  \
                                    __HIP_MEMORY_SCOPE_AGENT);                 \
        dst = u_.v;                                                            \
    } while (0)

__global__ __launch_bounds__(256, 1)
void lstm_kernel(const _Float16* __restrict__ xbuf,
                 _Float16* __restrict__ hb0, _Float16* __restrict__ hb1,
                 const float* __restrict__ Wf, const float* __restrict__ bfp,
                 const float* __restrict__ Wi, const float* __restrict__ bip,
                 const float* __restrict__ Wg, const float* __restrict__ bgp,
                 const float* __restrict__ Wo, const float* __restrict__ bop,
                 float* __restrict__ out,
                 unsigned* __restrict__ grp) {
    __shared__ _Float16 wsm[64 * 1024];   // 128 KB: full W slice, chunked

    const int tid = threadIdx.x;
    const int bid = blockIdx.x;
    const int mg = bid >> 7;
    const int ug = bid & 127;
    const int u0 = ug << 3;
    const int g  = mg * 4 + (bid & 3);    // barrier group: 32 blocks each

    const float* WSEL[4] = {Wf, Wi, Wg, Wo};

    // ---- stage W slice (32 cols x 2048 k) fp32 -> fp16 LDS, chunked ----
    // f16 idx = kc*1024 + tile*512 + quad*128 + row16*8 + j
    // (kc = k>>5, quad = (k>>3)&3, j = k&7, col = tile*16 + row16)
    // Read addr for lane L (= quad*16+row16): byte = kc*2048 + tile*1024 + L*16
    //   -> perfectly contiguous 16 B/lane -> zero bank conflicts.
    {
        const int col = tid & 31;                  // preact col
        const int kseg = tid >> 5;                 // 0..7, 256 k each
        const float* srcp = WSEL[col >> 3] + (size_t)(u0 + (col & 7)) * 2048
                          + kseg * 256;
        const int cbase = (col >> 4) * 512 + (col & 15) * 8;
#pragma unroll 8
        for (int k4 = 0; k4 < 256; k4 += 4) {
            const int k = kseg * 256 + k4;
            f4 v = *(const f4*)(srcp + k4);
            h4 hv = __builtin_convertvector(v, h4);
            *(h4*)&wsm[(k >> 5) * 1024 + cbase + ((k >> 3) & 3) * 128 + (k & 7)] = hv;
        }
    }

    // ---- per-lane constants ----
    const int lane  = tid & 63;
    const int wv    = tid >> 6;        // wave -> m-strip
    const int row16 = lane & 15;
    const int quad  = lane >> 4;
    const int uu    = lane & 7;

    __syncthreads();   // W staged (block-local)

    const float bias_f = bfp[u0 + uu];
    const float bias_i = bip[u0 + uu];
    const float bias_g = bgp[u0 + uu];
    const float bias_o = bop[u0 + uu];

    const int zrow = mg * 64 + wv * 16 + row16;
    const int boff = quad * 128 + row16 * 8;      // lane*8 f16 = lane*16 B
    const int drow = mg * 64 + wv * 16 + quad * 4;
    const bool writer = (lane & 8) == 0;
    const bool pstore = writer && ((uu & 1) == 0);   // even-unit writer: packs pair
    const bool himask = (lane & 8) != 0;

    const _Float16* hbv[2] = {hb0, hb1};
    const size_t aoff = (size_t)zrow * 1024 + quad * 8;
    const _Float16* xbase = xbuf + aoff;
    const size_t obase = (size_t)drow * 1024 + u0 + uu;   // row j adds j*1024

    float cc[4] = {0.f, 0.f, 0.f, 0.f};
    float hnv[4];                                  // step-t h values, stored late

    // ---- prologue: x-half for t = 0 (h(0)=0 already staged by prep) ----
    f4 a00 = {0.f,0.f,0.f,0.f}, a01 = {0.f,0.f,0.f,0.f};
    f4 a10 = {0.f,0.f,0.f,0.f}, a11 = {0.f,0.f,0.f,0.f};
    {
        const _Float16* xA = xbase;
        XHALF
    }

    for (int t = 0; t < 256; ++t) {
        if (t) bar_wait(grp, mg, (unsigned)(t - 1));   // h(t) released

        const _Float16* hA = hbv[t & 1] + aoff;
        unsigned* hwu = (unsigned*)hbv[(t + 1) & 1];

        // h half: k chunks 32..63 (the only h-dependent work); A via sc1 loads
#pragma unroll
        for (int kc = 32; kc < 64; kc += 2) {
            h8 av0, av1;
            LDH8(av0, (kc - 32) * 32);
            LDH8(av1, (kc - 32) * 32 + 32);
            h8 b00 = *(const h8*)&wsm[kc * 1024 + boff];
            h8 b10 = *(const h8*)&wsm[kc * 1024 + boff + 512];
            h8 b01 = *(const h8*)&wsm[(kc + 1) * 1024 + boff];
            h8 b11 = *(const h8*)&wsm[(kc + 1) * 1024 + boff + 512];
            a00 = __builtin_amdgcn_mfma_f32_16x16x32_f16(av0, b00, a00, 0, 0, 0);
            a10 = __builtin_amdgcn_mfma_f32_16x16x32_f16(av0, b10, a10, 0, 0, 0);
            a01 = __builtin_amdgcn_mfma_f32_16x16x32_f16(av1, b01, a01, 0, 0, 0);
            a11 = __builtin_amdgcn_mfma_f32_16x16x32_f16(av1, b11, a11, 0, 0, 0);
        }

        // ---- epilogue: gather gate pairs, activations, state update ----
        f4 s0 = a00 + a01;   // tile0: f|i preacts, col = lane&15
        f4 s1 = a10 + a11;   // tile1: g|o preacts
        float q0[4], q1[4];
#pragma unroll
        for (int j = 0; j < 4; ++j) {
            q0[j] = __shfl_xor(s0[j], 8, 64);
            q1[j] = __shfl_xor(s1[j], 8, 64);
        }
#pragma unroll
        for (int j = 0; j < 4; ++j) {
            float pf = himask ? q0[j] : s0[j];
            float pi = himask ? s0[j] : q0[j];
            float pg = himask ? q1[j] : s1[j];
            float po = himask ? s1[j] : q1[j];
            float fg = sigm(pf + bias_f);
            float ig = sigm(pi + bias_i);
            float gg = tanh_fast(pg + bias_g);
            float og = sigm(po + bias_o);
            float cn = fg * cc[j] + ig * gg;
            cc[j] = cn;
            float hn = og * tanh_fast(cn);
            hnv[j] = hn;
            // h(t+1) feedback: packed 2xfp16 agent-atomic store (sc1 ->
            // write-through to LLC; no dirty L2 line, no fence needed).
            float hp = __shfl_xor(hn, 1, 64);     // odd neighbor's value
            if (pstore) {
                _Float16 alo = (_Float16)hn, ahi = (_Float16)hp;
                unsigned short blo, bhi;
                __builtin_memcpy(&blo, &alo, 2);
                __builtin_memcpy(&bhi, &ahi, 2);
                unsigned pk = (unsigned)blo | ((unsigned)bhi << 16);
                __hip_atomic_store(&hwu[(obase >> 1) + (size_t)j * 512], pk,
                                   __ATOMIC_RELAXED, __HIP_MEMORY_SCOPE_AGENT);
            }
        }

        if (t < 255) {
            bar_arrive(grp, g);                  // vmcnt(0)-drain + arrival RMW
            // deferred nt out stores for step t: fire-and-forget, acks drain
            // at the NEXT bar_wait's trailing __syncthreads, overlapped with
            // the spin + x-half GEMM (off the critical path)
            if (writer) {
                float* outb = out + (size_t)t * 131072;
#pragma unroll
                for (int j = 0; j < 4; ++j)
                    __builtin_nontemporal_store(hnv[j], &outb[obase + (size_t)j * 1024]);
            }
            // x-half for t+1: h-independent, runs inside the barrier window
            a00 = (f4){0.f,0.f,0.f,0.f}; a01 = (f4){0.f,0.f,0.f,0.f};
            a10 = (f4){0.f,0.f,0.f,0.f}; a11 = (f4){0.f,0.f,0.f,0.f};
            const _Float16* xA = xbase + (size_t)(t + 1) * 131072;
            XHALF
        } else if (writer) {
            // t = 255: no barrier follows; store outputs[255] + hx directly
            float* outb = out + (size_t)255 * 131072;
#pragma unroll
            for (int j = 0; j < 4; ++j) {
                __builtin_nontemporal_store(hnv[j], &outb[obase + (size_t)j * 1024]);
                __builtin_nontemporal_store(hnv[j], &out[33554432 + obase + (size_t)j * 1024]);
            }
        }
    }
    // cx
    if (writer) {
#pragma unroll
        for (int j = 0; j < 4; ++j)
            __builtin_nontemporal_store(
                cc[j], &out[33554432 + 131072 + obase + (size_t)j * 1024]);
    }
}

extern "C" void kernel_launch(void* const* d_in, const int* in_sizes, int n_in,
                              void* d_out, int out_size, void* d_ws, size_t ws_size,
                              hipStream_t stream) {
    const float* x  = (const float*)d_in[0];
    const float* Wf = (const float*)d_in[1];
    const float* bf = (const float*)d_in[2];
    const float* Wi = (const float*)d_in[3];
    const float* bi = (const float*)d_in[4];
    const float* Wg = (const float*)d_in[5];
    const float* bg = (const float*)d_in[6];
    const float* Wo = (const float*)d_in[7];
    const float* bo = (const float*)d_in[8];
    float* out = (float*)d_out;

    unsigned char* ws = (unsigned char*)d_ws;
    unsigned* grp  = (unsigned*)ws;                       // 8 counters, 256-B stride
    _Float16* hb0  = (_Float16*)(ws + 4096);              // 128x1024 fp16 (256 KB)
    _Float16* hb1  = (_Float16*)(ws + 4096 + 262144);
    _Float16* xbuf = (_Float16*)(ws + 4096 + 524288);     // 256x128x1024 fp16 (64 MB)

    prep_kernel<<<2048, 256, 0, stream>>>(x, xbuf, grp, (unsigned*)hb0);
    lstm_kernel<<<NBLK, 256, 0, stream>>>(xbuf, hb0, hb1,
                                          Wf, bf, Wi, bi, Wg, bg, Wo, bo,
                                          out, grp);
}

// Round 8
// 3224.352 us; speedup vs baseline: 1.5977x; 1.1782x over previous
//
#include <hip/hip_runtime.h>

// ---------- types ----------
typedef _Float16 h8 __attribute__((ext_vector_type(8)));
typedef _Float16 h4 __attribute__((ext_vector_type(4)));
typedef float    f4 __attribute__((ext_vector_type(4)));
typedef unsigned long long u64;

#define NBLK 256   // persistent grid = 256 blocks = 1 per CU

__device__ __forceinline__ float sigm(float x) {
    return 1.0f / (1.0f + __expf(-x));
}
__device__ __forceinline__ float tanh_fast(float x) {
    return 1.0f - 2.0f / (__expf(2.0f * x) + 1.0f);   // saturates correctly at +/-inf
}

// FENCE-FREE grid barrier (per-mg, 4 groups x 32 blocks). Measured R7:
// 19.4 -> 14.4 us/step vs the wbl2/inv version. Residual theory: the bulk h
// loads were 8-B ATOMIC loads (LLC atomic pipe, low throughput). This round:
// ROTATING h buffers (one per timestep) make every h address write-once/
// read-once -> consumers can use PLAIN cached 16-B loads with no stale-line
// hazard (L1/L2 never saw the address before; producer sc1 stores put fresh
// data at the LLC which the miss path reads). Barrier + store side unchanged.
__device__ __forceinline__ void bar_arrive(unsigned* grp, int g) {
    __syncthreads();   // s_waitcnt vmcnt(0): all sc1 h-stores acked at LLC
    if (threadIdx.x == 0) {
        __hip_atomic_fetch_add(&grp[g * 64], 1u, __ATOMIC_RELAXED,
                               __HIP_MEMORY_SCOPE_AGENT);
    }
    // NO trailing sync: other waves fall through into h-independent work.
}
__device__ __forceinline__ void bar_wait(unsigned* grp, int mg, unsigned barno) {
    if (threadIdx.x == 0) {
        const unsigned tgt = (barno + 1u) * 128u;   // 4 groups x 32 blocks per round
        unsigned* base = &grp[mg * 4 * 64];
        unsigned spins = 0;
        for (;;) {
            unsigned s0 = __hip_atomic_load(&base[0],   __ATOMIC_RELAXED,
                                            __HIP_MEMORY_SCOPE_AGENT);
            unsigned s1 = __hip_atomic_load(&base[64],  __ATOMIC_RELAXED,
                                            __HIP_MEMORY_SCOPE_AGENT);
            unsigned s2 = __hip_atomic_load(&base[128], __ATOMIC_RELAXED,
                                            __HIP_MEMORY_SCOPE_AGENT);
            unsigned s3 = __hip_atomic_load(&base[192], __ATOMIC_RELAXED,
                                            __HIP_MEMORY_SCOPE_AGENT);
            if (s0 + s1 + s2 + s3 >= tgt) break;
            __builtin_amdgcn_s_sleep(2);
            if (++spins > (1u << 24)) break;   // safety valve: corrupt-but-return
        }
    }
    __syncthreads();   // also drains the overlapped nt out-stores + x loads
}

// ---------- prep: zero counters + h buffer 0, fp32 x -> fp16 ----------
__global__ void prep_kernel(const float* __restrict__ x, _Float16* __restrict__ xbuf,
                            unsigned* __restrict__ ctr, unsigned* __restrict__ hb0u) {
    const int gtid = blockIdx.x * blockDim.x + threadIdx.x;
    if (gtid < 1024) ctr[gtid] = 0u;          // grp[8] (256-B stride)
    if (gtid < 65536) hb0u[gtid] = 0u;        // h(0): 128x1024 fp16 = 256 KB
    const f4* src = (const f4*)x;
    h4* dst = (h4*)xbuf;
    const int stride = gridDim.x * blockDim.x;    // 524288
    for (int i = gtid; i < 8388608; i += stride)  // T*B*D/4
        dst[i] = __builtin_convertvector(src[i], h4);
}

// ---------- persistent LSTM ----------
// 256 blocks x 256 threads. Block b: mg = b>>7 (rows mg*64..+63), ug = b&127,
// units u0 = ug*8 .. +7, all 4 gates -> 32 preact cols (2 MFMA n-tiles).
// ALL of W (K=2048) in LDS, conflict-free chunk layout (see staging below).
// Loop structure per step t:
//   [a-regs already hold the x-half partial sums for step t]
//   bar_wait(t-1)            <- h(t) arrival count reached
//   h-half MFMAs (kc 32..63) <- ROT: plain cached h8 loads (fresh addresses)
//                               PP fallback: sc1 atomic loads (R7-measured)
//   epilogue: activations, c/h update, h(t+1) via packed sc1 atomic stores
//   bar_arrive(t)            <- vmcnt(0)-drained stores, then counter RMW
//   nt out stores for step t <- fire-and-forget, drain overlapped w/ next spin
//   x-half MFMAs for t+1     <- executes INSIDE the barrier window
#define XHALF                                                                  \
    _Pragma("unroll")                                                          \
    for (int kc = 0; kc < 32; kc += 2) {                                       \
        h8 av0 = *(const h8*)(xA + kc * 32);                                   \
        h8 av1 = *(const h8*)(xA + kc * 32 + 32);                              \
        h8 b00 = *(const h8*)&wsm[kc * 1024 + boff];                           \
        h8 b10 = *(const h8*)&wsm[kc * 1024 + boff + 512];                     \
        h8 b01 = *(const h8*)&wsm[(kc + 1) * 1024 + boff];                     \
        h8 b11 = *(const h8*)&wsm[(kc + 1) * 1024 + boff + 512];               \
        a00 = __builtin_amdgcn_mfma_f32_16x16x32_f16(av0, b00, a00, 0, 0, 0);  \
        a10 = __builtin_amdgcn_mfma_f32_16x16x32_f16(av0, b10, a10, 0, 0, 0);  \
        a01 = __builtin_amdgcn_mfma_f32_16x16x32_f16(av1, b01, a01, 0, 0, 0);  \
        a11 = __builtin_amdgcn_mfma_f32_16x16x32_f16(av1, b11, a11, 0, 0, 0);  \
    }

// sc1 (LLC-coherent) h8 load: two agent-relaxed u64 atomic loads (PP fallback).
#define LDH8(dst, elemoff)                                                     \
    do {                                                                       \
        union { u64 q[2]; h8 v; } u_;                                          \
        u64* p_ = (u64*)(hA + (elemoff));                                      \
        u_.q[0] = __hip_atomic_load(p_,     __ATOMIC_RELAXED,                  \
                                    __HIP_MEMORY_SCOPE_AGENT);                 \
        u_.q[1] = __hip_atomic_load(p_ + 1, __ATOMIC_RELAXED,                  \
                                    __HIP_MEMORY_SCOPE_AGENT);                 \
        dst = u_.v;                                                            \
    } while (0)

template<bool ROT>
__global__ __launch_bounds__(256, 1)
void lstm_kernel(const _Float16* __restrict__ xbuf,
                 _Float16* __restrict__ hb0, _Float16* __restrict__ hb1,
                 const float* __restrict__ Wf, const float* __restrict__ bfp,
                 const float* __restrict__ Wi, const float* __restrict__ bip,
                 const float* __restrict__ Wg, const float* __restrict__ bgp,
                 const float* __restrict__ Wo, const float* __restrict__ bop,
                 float* __restrict__ out,
                 unsigned* __restrict__ grp) {
    __shared__ _Float16 wsm[64 * 1024];   // 128 KB: full W slice, chunked

    const int tid = threadIdx.x;
    const int bid = blockIdx.x;
    const int mg = bid >> 7;
    const int ug = bid & 127;
    const int u0 = ug << 3;
    const int g  = mg * 4 + (bid & 3);    // barrier group: 32 blocks each

    const float* WSEL[4] = {Wf, Wi, Wg, Wo};

    // ---- stage W slice (32 cols x 2048 k) fp32 -> fp16 LDS, chunked ----
    // f16 idx = kc*1024 + tile*512 + quad*128 + row16*8 + j
    // (kc = k>>5, quad = (k>>3)&3, j = k&7, col = tile*16 + row16)
    // Read addr for lane L (= quad*16+row16): byte = kc*2048 + tile*1024 + L*16
    //   -> perfectly contiguous 16 B/lane -> zero bank conflicts.
    {
        const int col = tid & 31;                  // preact col
        const int kseg = tid >> 5;                 // 0..7, 256 k each
        const float* srcp = WSEL[col >> 3] + (size_t)(u0 + (col & 7)) * 2048
                          + kseg * 256;
        const int cbase = (col >> 4) * 512 + (col & 15) * 8;
#pragma unroll 8
        for (int k4 = 0; k4 < 256; k4 += 4) {
            const int k = kseg * 256 + k4;
            f4 v = *(const f4*)(srcp + k4);
            h4 hv = __builtin_convertvector(v, h4);
            *(h4*)&wsm[(k >> 5) * 1024 + cbase + ((k >> 3) & 3) * 128 + (k & 7)] = hv;
        }
    }

    // ---- per-lane constants ----
    const int lane  = tid & 63;
    const int wv    = tid >> 6;        // wave -> m-strip
    const int row16 = lane & 15;
    const int quad  = lane >> 4;
    const int uu    = lane & 7;

    __syncthreads();   // W staged (block-local)

    const float bias_f = bfp[u0 + uu];
    const float bias_i = bip[u0 + uu];
    const float bias_g = bgp[u0 + uu];
    const float bias_o = bop[u0 + uu];

    const int zrow = mg * 64 + wv * 16 + row16;
    const int boff = quad * 128 + row16 * 8;      // lane*8 f16 = lane*16 B
    const int drow = mg * 64 + wv * 16 + quad * 4;
    const bool writer = (lane & 8) == 0;
    const bool pstore = writer && ((uu & 1) == 0);   // even-unit writer: packs pair
    const bool himask = (lane & 8) != 0;

    const _Float16* hbv[2] = {hb0, hb1};
    const size_t aoff = (size_t)zrow * 1024 + quad * 8;
    const _Float16* xbase = xbuf + aoff;
    const size_t obase = (size_t)drow * 1024 + u0 + uu;   // row j adds j*1024

    float cc[4] = {0.f, 0.f, 0.f, 0.f};
    float hnv[4];                                  // step-t h values, stored late

    // ---- prologue: x-half for t = 0 (h(0)=0 already staged by prep) ----
    f4 a00 = {0.f,0.f,0.f,0.f}, a01 = {0.f,0.f,0.f,0.f};
    f4 a10 = {0.f,0.f,0.f,0.f}, a11 = {0.f,0.f,0.f,0.f};
    {
        const _Float16* xA = xbase;
        XHALF
    }

    for (int t = 0; t < 256; ++t) {
        if (t) bar_wait(grp, mg, (unsigned)(t - 1));   // h(t) released

        const _Float16* hA = (ROT ? hb0 + (size_t)t * 131072 : hbv[t & 1]) + aoff;
        unsigned* hwu = (unsigned*)(ROT ? hb0 + (size_t)(t + 1) * 131072
                                        : hbv[(t + 1) & 1]);

        // h half: k chunks 32..63 (the only h-dependent work)
#pragma unroll
        for (int kc = 32; kc < 64; kc += 2) {
            h8 av0, av1;
            if constexpr (ROT) {
                // plain cached loads: address is write-once/read-once, so no
                // stale L1/L2 line can exist; miss path reads fresh LLC data
                av0 = *(const h8*)(hA + (kc - 32) * 32);
                av1 = *(const h8*)(hA + (kc - 32) * 32 + 32);
            } else {
                LDH8(av0, (kc - 32) * 32);
                LDH8(av1, (kc - 32) * 32 + 32);
            }
            h8 b00 = *(const h8*)&wsm[kc * 1024 + boff];
            h8 b10 = *(const h8*)&wsm[kc * 1024 + boff + 512];
            h8 b01 = *(const h8*)&wsm[(kc + 1) * 1024 + boff];
            h8 b11 = *(const h8*)&wsm[(kc + 1) * 1024 + boff + 512];
            a00 = __builtin_amdgcn_mfma_f32_16x16x32_f16(av0, b00, a00, 0, 0, 0);
            a10 = __builtin_amdgcn_mfma_f32_16x16x32_f16(av0, b10, a10, 0, 0, 0);
            a01 = __builtin_amdgcn_mfma_f32_16x16x32_f16(av1, b01, a01, 0, 0, 0);
            a11 = __builtin_amdgcn_mfma_f32_16x16x32_f16(av1, b11, a11, 0, 0, 0);
        }

        // ---- epilogue: gather gate pairs, activations, state update ----
        f4 s0 = a00 + a01;   // tile0: f|i preacts, col = lane&15
        f4 s1 = a10 + a11;   // tile1: g|o preacts
        float q0[4], q1[4];
#pragma unroll
        for (int j = 0; j < 4; ++j) {
            q0[j] = __shfl_xor(s0[j], 8, 64);
            q1[j] = __shfl_xor(s1[j], 8, 64);
        }
#pragma unroll
        for (int j = 0; j < 4; ++j) {
            float pf = himask ? q0[j] : s0[j];
            float pi = himask ? s0[j] : q0[j];
            float pg = himask ? q1[j] : s1[j];
            float po = himask ? s1[j] : q1[j];
            float fg = sigm(pf + bias_f);
            float ig = sigm(pi + bias_i);
            float gg = tanh_fast(pg + bias_g);
            float og = sigm(po + bias_o);
            float cn = fg * cc[j] + ig * gg;
            cc[j] = cn;
            float hn = og * tanh_fast(cn);
            hnv[j] = hn;
            // h(t+1) feedback: packed 2xfp16 agent-atomic store (sc1 ->
            // write-through to LLC; no dirty L2 line, no fence needed).
            float hp = __shfl_xor(hn, 1, 64);     // odd neighbor's value
            if (pstore) {
                _Float16 alo = (_Float16)hn, ahi = (_Float16)hp;
                unsigned short blo, bhi;
                __builtin_memcpy(&blo, &alo, 2);
                __builtin_memcpy(&bhi, &ahi, 2);
                unsigned pk = (unsigned)blo | ((unsigned)bhi << 16);
                __hip_atomic_store(&hwu[(obase >> 1) + (size_t)j * 512], pk,
                                   __ATOMIC_RELAXED, __HIP_MEMORY_SCOPE_AGENT);
            }
        }

        if (t < 255) {
            bar_arrive(grp, g);                  // vmcnt(0)-drain + arrival RMW
            // deferred nt out stores for step t: fire-and-forget, acks drain
            // at the NEXT bar_wait's trailing __syncthreads, overlapped with
            // the spin + x-half GEMM (off the critical path)
            if (writer) {
                float* outb = out + (size_t)t * 131072;
#pragma unroll
                for (int j = 0; j < 4; ++j)
                    __builtin_nontemporal_store(hnv[j], &outb[obase + (size_t)j * 1024]);
            }
            // x-half for t+1: h-independent, runs inside the barrier window
            a00 = (f4){0.f,0.f,0.f,0.f}; a01 = (f4){0.f,0.f,0.f,0.f};
            a10 = (f4){0.f,0.f,0.f,0.f}; a11 = (f4){0.f,0.f,0.f,0.f};
            const _Float16* xA = xbase + (size_t)(t + 1) * 131072;
            XHALF
        } else if (writer) {
            // t = 255: no barrier follows; store outputs[255] + hx directly
            float* outb = out + (size_t)255 * 131072;
#pragma unroll
            for (int j = 0; j < 4; ++j) {
                __builtin_nontemporal_store(hnv[j], &outb[obase + (size_t)j * 1024]);
                __builtin_nontemporal_store(hnv[j], &out[33554432 + obase + (size_t)j * 1024]);
            }
        }
    }
    // cx
    if (writer) {
#pragma unroll
        for (int j = 0; j < 4; ++j)
            __builtin_nontemporal_store(
                cc[j], &out[33554432 + 131072 + obase + (size_t)j * 1024]);
    }
}

extern "C" void kernel_launch(void* const* d_in, const int* in_sizes, int n_in,
                              void* d_out, int out_size, void* d_ws, size_t ws_size,
                              hipStream_t stream) {
    const float* x  = (const float*)d_in[0];
    const float* Wf = (const float*)d_in[1];
    const float* bf = (const float*)d_in[2];
    const float* Wi = (const float*)d_in[3];
    const float* bi = (const float*)d_in[4];
    const float* Wg = (const float*)d_in[5];
    const float* bg = (const float*)d_in[6];
    const float* Wo = (const float*)d_in[7];
    const float* bo = (const float*)d_in[8];
    float* out = (float*)d_out;

    unsigned char* ws = (unsigned char*)d_ws;
    unsigned* grp  = (unsigned*)ws;                       // 8 counters, 256-B stride
    _Float16* hbase = (_Float16*)(ws + 4096);             // rot: 257 bufs / pp: hb0

    // Rotating layout: grp 4 KB | h buffers 257 x 256 KB | xbuf 64 MB
    const size_t HROT = 257ull * 262144ull;               // 67,371,008 B
    const size_t ROT_NEED = 4096ull + HROT + 67108864ull; // ~131.5 MB
    const bool rot = (ws_size >= ROT_NEED);

    _Float16* hb1  = (_Float16*)(ws + 4096 + 262144);     // pp fallback only
    _Float16* xbuf = rot ? (_Float16*)(ws + 4096 + HROT)
                         : (_Float16*)(ws + 4096 + 524288);

    prep_kernel<<<2048, 256, 0, stream>>>(x, xbuf, grp, (unsigned*)hbase);
    if (rot)
        lstm_kernel<true><<<NBLK, 256, 0, stream>>>(xbuf, hbase, hb1,
                                                    Wf, bf, Wi, bi, Wg, bg, Wo, bo,
                                                    out, grp);
    else
        lstm_kernel<false><<<NBLK, 256, 0, stream>>>(xbuf, hbase, hb1,
                                                     Wf, bf, Wi, bi, Wg, bg, Wo, bo,
                                                     out, grp);
}